// Round 4
// baseline (844.457 us; speedup 1.0000x reference)
//
#include <hip/hip_runtime.h>
#include <math.h>

#define N_NODES 50000
#define N_EDGES 800000
#define D_IN    256
#define D_HID   128
#define D_OUT   64

typedef unsigned int u32;

__device__ __forceinline__ float bflo(u32 u) {
    union { u32 i; float f; } c; c.i = u << 16; return c.f;
}
__device__ __forceinline__ float bfhi(u32 u) {
    union { u32 i; float f; } c; c.i = u & 0xffff0000u; return c.f;
}
__device__ __forceinline__ u32 pack_bf2(float a, float b) {
    union { float f; u32 i; } ca, cb; ca.f = a; cb.f = b;
    u32 ra = (ca.i + 0x7fffu + ((ca.i >> 16) & 1u)) >> 16;
    u32 rb = (cb.i + 0x7fffu + ((cb.i >> 16) & 1u)) & 0xffff0000u;
    return ra | rb;
}

// ---------------- edge dtype detection ----------------
__global__ void k_detect(const void* __restrict__ ei, int* __restrict__ flag) {
    int t = threadIdx.x;
    int v = ((const int*)ei)[2 * t + 1];
    if (v != 0) atomicOr(flag, 1);
}

__device__ __forceinline__ int edge_at(const void* ei, int is64, int which, int i) {
    if (is64) return (int)((const long long*)ei)[(size_t)which * N_EDGES + i];
    return ((const int*)ei)[which * N_EDGES + i];
}

// ---------------- degree / CSR build ----------------

__global__ void k_count(const void* __restrict__ ei, const int* __restrict__ flag,
                        int* __restrict__ cnt) {
    int i = blockIdx.x * blockDim.x + threadIdx.x;
    int is64 = (flag[0] == 0);
    if (i < N_EDGES) atomicAdd(&cnt[edge_at(ei, is64, 1, i)], 1);
}

__global__ void k_dinv(const int* __restrict__ cnt, float* __restrict__ dinv) {
    int i = blockIdx.x * blockDim.x + threadIdx.x;
    if (i < N_NODES) dinv[i] = rsqrtf(1.0f + (float)cnt[i]);
}

#define SCAN_B 256
__global__ void k_scan1(const int* __restrict__ cnt, int* __restrict__ ex,
                        int* __restrict__ partials, int n) {
    __shared__ int sm[SCAN_B];
    int t = threadIdx.x;
    int i = blockIdx.x * SCAN_B + t;
    int v = (i < n) ? cnt[i] : 0;
    sm[t] = v; __syncthreads();
    for (int off = 1; off < SCAN_B; off <<= 1) {
        int add = (t >= off) ? sm[t - off] : 0;
        __syncthreads();
        sm[t] += add;
        __syncthreads();
    }
    if (i < n) ex[i] = sm[t] - v;
    if (t == SCAN_B - 1) partials[blockIdx.x] = sm[t];
}

__global__ void k_scan2(int* __restrict__ partials, int nb) {
    __shared__ int sm[SCAN_B];
    int t = threadIdx.x;
    int v = (t < nb) ? partials[t] : 0;
    sm[t] = v; __syncthreads();
    for (int off = 1; off < SCAN_B; off <<= 1) {
        int add = (t >= off) ? sm[t - off] : 0;
        __syncthreads();
        sm[t] += add;
        __syncthreads();
    }
    if (t < nb) partials[t] = sm[t] - v;
}

__global__ void k_scan3(int* __restrict__ ex, const int* __restrict__ partials, int n) {
    int i = blockIdx.x * SCAN_B + threadIdx.x;
    if (i < n) ex[i] += partials[blockIdx.x];
}

__global__ void k_fill(const void* __restrict__ ei, const int* __restrict__ flag,
                       const int* __restrict__ rowstart, int* __restrict__ cursor,
                       int* __restrict__ colidx) {
    int i = blockIdx.x * blockDim.x + threadIdx.x;
    int is64 = (flag[0] == 0);
    if (i < N_EDGES) {
        int s = edge_at(ei, is64, 0, i);
        int d = edge_at(ei, is64, 1, i);
        int pos = rowstart[d] + atomicAdd(&cursor[d], 1);
        colidx[pos] = s;
    }
}

// ---- GEMM: Cp[r, :] = pack_bf16( (A[r,:] @ W) * dinv[r] ), f32 math ----
// 8x8 microtile (1.0 FMA per LDS byte), MT=64, KT=16.
// Row blocks {r0, r0+32}, col blocks {c0, c0+NF/2}: all LDS reads <=2-way.

template <int K, int NF>
__global__ void k_gemm_s(const float* __restrict__ A, const float* __restrict__ W,
                         const float* __restrict__ dinv, u32* __restrict__ Cp, int M) {
    constexpr int MT = 64;
    constexpr int KT = 16;
    constexpr int NTHREADS = MT * NF / 64;      // 128 (NF=128) or 64 (NF=64)
    constexpr int CGRPS = NF / 8;               // col groups of 4
    __shared__ float wl[KT][NF];
    __shared__ float xl[KT][MT];

    const int t = threadIdx.x;
    const int m0 = blockIdx.x * MT;
    const int c0 = (t % CGRPS) * 4;
    const int r0 = (t / CGRPS) * 4;             // 0..28

    float acc[2][2][4][4] = {};                 // [rowblk][colblk][ri][ci]

    for (int k0 = 0; k0 < K; k0 += KT) {
        // stage W chunk: consecutive lanes -> consecutive cols (coalesced, conflict-free)
        constexpr int WLOADS = KT * NF / 4;
        #pragma unroll
        for (int idx = t; idx < WLOADS; idx += NTHREADS) {
            int kk = idx / (NF / 4);
            int ff = (idx % (NF / 4)) * 4;
            *(float4*)&wl[kk][ff] = *(const float4*)&W[(k0 + kk) * NF + ff];
        }
        // stage A chunk transposed; n fastest across lanes -> conflict-free LDS stores
        constexpr int XLOADS = MT * KT / 4;
        #pragma unroll
        for (int idx = t; idx < XLOADS; idx += NTHREADS) {
            int n  = idx % MT;
            int kc = (idx / MT) * 4;
            float4 xv = make_float4(0.f, 0.f, 0.f, 0.f);
            int row = m0 + n;
            if (row < M) xv = *(const float4*)&A[row * K + k0 + kc];
            xl[kc + 0][n] = xv.x; xl[kc + 1][n] = xv.y;
            xl[kc + 2][n] = xv.z; xl[kc + 3][n] = xv.w;
        }
        __syncthreads();
        #pragma unroll
        for (int kk = 0; kk < KT; ++kk) {
            float4 xa = *(const float4*)&xl[kk][r0];
            float4 xb = *(const float4*)&xl[kk][r0 + 32];
            float4 wa = *(const float4*)&wl[kk][c0];
            float4 wb = *(const float4*)&wl[kk][c0 + NF / 2];
            const float xr[2][4] = {{xa.x, xa.y, xa.z, xa.w}, {xb.x, xb.y, xb.z, xb.w}};
            const float wc[2][4] = {{wa.x, wa.y, wa.z, wa.w}, {wb.x, wb.y, wb.z, wb.w}};
            #pragma unroll
            for (int rb = 0; rb < 2; ++rb)
                #pragma unroll
                for (int cb = 0; cb < 2; ++cb)
                    #pragma unroll
                    for (int ri = 0; ri < 4; ++ri)
                        #pragma unroll
                        for (int ci = 0; ci < 4; ++ci)
                            acc[rb][cb][ri][ci] += xr[rb][ri] * wc[cb][ci];
        }
        __syncthreads();
    }

    #pragma unroll
    for (int rb = 0; rb < 2; ++rb) {
        #pragma unroll
        for (int ri = 0; ri < 4; ++ri) {
            int row = m0 + rb * 32 + r0 + ri;
            if (row < M) {
                float s = dinv[row];
                #pragma unroll
                for (int cb = 0; cb < 2; ++cb) {
                    uint2 o;
                    o.x = pack_bf2(acc[rb][cb][ri][0] * s, acc[rb][cb][ri][1] * s);
                    o.y = pack_bf2(acc[rb][cb][ri][2] * s, acc[rb][cb][ri][3] * s);
                    *(uint2*)&Cp[(size_t)row * (NF / 2) + (c0 + cb * (NF / 2)) / 2] = o;
                }
            }
        }
    }
}

// ---------------- fused aggregate + bias (+relu) + sigmoid gate ----------------
// hs rows are pre-scaled by dinv[row]; agg = dv * (hs[v] + sum hs[neighbor]).

// layer 1: 128 feats = 64 u32/row. One wave per node; lane l = feats (2l, 2l+1).
__global__ void k_agg1(const u32* __restrict__ hs, const int* __restrict__ rowstart,
                       const int* __restrict__ cnt, const int* __restrict__ colidx,
                       const float* __restrict__ dinv,
                       const float* __restrict__ b, const float* __restrict__ aw,
                       const float* __restrict__ ab, float* __restrict__ out) {
    int v = blockIdx.x;
    int l = threadIdx.x;
    float dv = dinv[v];
    u32 su = hs[(size_t)v * 64 + l];
    float ax = bflo(su), ay = bfhi(su);
    int start = rowstart[v], len = cnt[v];
    const int* cx = colidx + start;
    int j = 0;
    for (; j + 4 <= len; j += 4) {
        int s0 = cx[j], s1 = cx[j + 1], s2 = cx[j + 2], s3 = cx[j + 3];
        u32 u0 = hs[(size_t)s0 * 64 + l];
        u32 u1 = hs[(size_t)s1 * 64 + l];
        u32 u2 = hs[(size_t)s2 * 64 + l];
        u32 u3 = hs[(size_t)s3 * 64 + l];
        ax += bflo(u0) + bflo(u1) + bflo(u2) + bflo(u3);
        ay += bfhi(u0) + bfhi(u1) + bfhi(u2) + bfhi(u3);
    }
    for (; j < len; ++j) {
        u32 u = hs[(size_t)cx[j] * 64 + l];
        ax += bflo(u); ay += bfhi(u);
    }
    float2 bp = ((const float2*)b)[l];
    ax = fmaxf(ax * dv + bp.x, 0.0f);
    ay = fmaxf(ay * dv + bp.y, 0.0f);
    float2 ap = ((const float2*)aw)[l];
    float p = ax * ap.x + ay * ap.y;
    for (int off = 32; off; off >>= 1) p += __shfl_xor(p, off);
    float g = 1.0f / (1.0f + expf(-(p + ab[0])));
    ((float2*)out)[(size_t)v * 64 + l] = make_float2(ax * g, ay * g);
}

// layer 2: 64 feats = 32 u32/row. One wave per node, 2 half-waves on
// alternating neighbors (2 rows in flight, x2 unroll = 4).
__global__ void k_agg2(const u32* __restrict__ hs, const int* __restrict__ rowstart,
                       const int* __restrict__ cnt, const int* __restrict__ colidx,
                       const float* __restrict__ dinv,
                       const float* __restrict__ b, const float* __restrict__ aw,
                       const float* __restrict__ ab, float* __restrict__ out) {
    int v = blockIdx.x;
    int l = threadIdx.x;
    int c = l & 31, half = l >> 5;
    float dv = dinv[v];
    float ax = 0.0f, ay = 0.0f;
    if (half == 0) {
        u32 su = hs[(size_t)v * 32 + c];
        ax = bflo(su); ay = bfhi(su);
    }
    int start = rowstart[v], len = cnt[v];
    const int* cx = colidx + start;
    int j = half;
    for (; j + 2 < len; j += 4) {
        int s0 = cx[j], s1 = cx[j + 2];
        u32 u0 = hs[(size_t)s0 * 32 + c];
        u32 u1 = hs[(size_t)s1 * 32 + c];
        ax += bflo(u0) + bflo(u1);
        ay += bfhi(u0) + bfhi(u1);
    }
    if (j < len) {
        u32 u = hs[(size_t)cx[j] * 32 + c];
        ax += bflo(u); ay += bfhi(u);
    }
    ax += __shfl_xor(ax, 32);
    ay += __shfl_xor(ay, 32);
    float2 bp = ((const float2*)b)[c];
    ax = ax * dv + bp.x;
    ay = ay * dv + bp.y;
    float2 ap = ((const float2*)aw)[c];
    float p = ax * ap.x + ay * ap.y;
    for (int off = 16; off; off >>= 1) p += __shfl_xor(p, off);
    float g = 1.0f / (1.0f + expf(-(p + ab[0])));
    if (half == 0) ((float2*)out)[(size_t)v * 32 + c] = make_float2(ax * g, ay * g);
}

// ---------------- launch ----------------

static inline size_t align_up(size_t x, size_t a) { return (x + a - 1) & ~(a - 1); }

extern "C" void kernel_launch(void* const* d_in, const int* in_sizes, int n_in,
                              void* d_out, int out_size, void* d_ws, size_t ws_size,
                              hipStream_t stream) {
    const float* x   = (const float*)d_in[0];
    const void*  ei  = d_in[1];
    const float* W1  = (const float*)d_in[2];
    const float* b1  = (const float*)d_in[3];
    const float* W2  = (const float*)d_in[4];
    const float* b2  = (const float*)d_in[5];
    const float* aw1 = (const float*)d_in[6];
    const float* ab1 = (const float*)d_in[7];
    const float* aw2 = (const float*)d_in[8];
    const float* ab2 = (const float*)d_in[9];
    float* out = (float*)d_out;

    char* w = (char*)d_ws;
    size_t off = 0;
    int*   flag     = (int*)(w + off); off = align_up(off + 4, 256);
    int*   cnt      = (int*)(w + off); off = align_up(off + N_NODES * 4, 256);
    int*   rowstart = (int*)(w + off); off = align_up(off + N_NODES * 4, 256);
    int*   cursor   = (int*)(w + off); off = align_up(off + N_NODES * 4, 256);
    int*   partials = (int*)(w + off); off = align_up(off + 1024 * 4, 256);
    float* dinv     = (float*)(w + off); off = align_up(off + N_NODES * 4, 256);
    int*   colidx   = (int*)(w + off); off = align_up(off + (size_t)N_EDGES * 4, 256);
    u32*   h1s      = (u32*)(w + off); off = align_up(off + (size_t)N_NODES * 64 * 4, 256);
    float* h1g      = (float*)(w + off); off = align_up(off + (size_t)N_NODES * D_HID * 4, 256);
    u32*   h2s      = (u32*)(w + off); off = align_up(off + (size_t)N_NODES * 32 * 4, 256);
    (void)ws_size; (void)out_size; (void)n_in; (void)in_sizes;

    hipMemsetAsync(flag, 0, 4, stream);
    hipMemsetAsync(cnt, 0, N_NODES * 4, stream);
    hipMemsetAsync(cursor, 0, N_NODES * 4, stream);

    const int eb = (N_EDGES + 255) / 256;
    const int nb = (N_NODES + 255) / 256;
    const int sb = (N_NODES + SCAN_B - 1) / SCAN_B;

    k_detect<<<1, 256, 0, stream>>>(ei, flag);
    k_count<<<eb, 256, 0, stream>>>(ei, flag, cnt);
    k_dinv<<<nb, 256, 0, stream>>>(cnt, dinv);
    k_scan1<<<sb, SCAN_B, 0, stream>>>(cnt, rowstart, partials, N_NODES);
    k_scan2<<<1, SCAN_B, 0, stream>>>(partials, sb);
    k_scan3<<<sb, SCAN_B, 0, stream>>>(rowstart, partials, N_NODES);
    k_fill<<<eb, 256, 0, stream>>>(ei, flag, rowstart, cursor, colidx);

    const int gb = (N_NODES + 63) / 64;   // 782 tiles of 64 rows

    // layer 1: h1s = pack_bf16((x @ W1) * dinv)
    k_gemm_s<D_IN, D_HID><<<gb, 128, 0, stream>>>(x, W1, dinv, h1s, N_NODES);
    k_agg1<<<N_NODES, 64, 0, stream>>>(h1s, rowstart, cnt, colidx, dinv, b1, aw1, ab1, h1g);

    // layer 2: h2s = pack_bf16((h1g @ W2) * dinv)
    k_gemm_s<D_HID, D_OUT><<<gb, 64, 0, stream>>>(h1g, W2, dinv, h2s, N_NODES);
    k_agg2<<<N_NODES, 64, 0, stream>>>(h2s, rowstart, cnt, colidx, dinv, b2, aw2, ab2, out);
}

// Round 6
// 568.008 us; speedup vs baseline: 1.4867x; 1.4867x over previous
//
#include <hip/hip_runtime.h>
#include <math.h>

#define N_NODES 50000
#define N_EDGES 800000
#define D_IN    256
#define D_HID   128
#define D_OUT   64

typedef unsigned int u32;

__device__ __forceinline__ float bflo(u32 u) {
    union { u32 i; float f; } c; c.i = u << 16; return c.f;
}
__device__ __forceinline__ float bfhi(u32 u) {
    union { u32 i; float f; } c; c.i = u & 0xffff0000u; return c.f;
}
__device__ __forceinline__ u32 pack_bf2(float a, float b) {
    union { float f; u32 i; } ca, cb; ca.f = a; cb.f = b;
    u32 ra = (ca.i + 0x7fffu + ((ca.i >> 16) & 1u)) >> 16;
    u32 rb = (cb.i + 0x7fffu + ((cb.i >> 16) & 1u)) & 0xffff0000u;
    return ra | rb;
}

// ---------------- edge dtype detection ----------------
__global__ void k_detect(const void* __restrict__ ei, int* __restrict__ flag) {
    int t = threadIdx.x;
    int v = ((const int*)ei)[2 * t + 1];
    if (v != 0) atomicOr(flag, 1);
}

__device__ __forceinline__ int edge_at(const void* ei, int is64, int which, int i) {
    if (is64) return (int)((const long long*)ei)[(size_t)which * N_EDGES + i];
    return ((const int*)ei)[which * N_EDGES + i];
}

// ---------------- degree / CSR build ----------------

__global__ void k_count(const void* __restrict__ ei, const int* __restrict__ flag,
                        int* __restrict__ cnt) {
    int i = blockIdx.x * blockDim.x + threadIdx.x;
    int is64 = (flag[0] == 0);
    if (i < N_EDGES) atomicAdd(&cnt[edge_at(ei, is64, 1, i)], 1);
}

__global__ void k_dinv(const int* __restrict__ cnt, float* __restrict__ dinv) {
    int i = blockIdx.x * blockDim.x + threadIdx.x;
    if (i < N_NODES) dinv[i] = rsqrtf(1.0f + (float)cnt[i]);
}

#define SCAN_B 256
__global__ void k_scan1(const int* __restrict__ cnt, int* __restrict__ ex,
                        int* __restrict__ partials, int n) {
    __shared__ int sm[SCAN_B];
    int t = threadIdx.x;
    int i = blockIdx.x * SCAN_B + t;
    int v = (i < n) ? cnt[i] : 0;
    sm[t] = v; __syncthreads();
    for (int off = 1; off < SCAN_B; off <<= 1) {
        int add = (t >= off) ? sm[t - off] : 0;
        __syncthreads();
        sm[t] += add;
        __syncthreads();
    }
    if (i < n) ex[i] = sm[t] - v;
    if (t == SCAN_B - 1) partials[blockIdx.x] = sm[t];
}

__global__ void k_scan2(int* __restrict__ partials, int nb) {
    __shared__ int sm[SCAN_B];
    int t = threadIdx.x;
    int v = (t < nb) ? partials[t] : 0;
    sm[t] = v; __syncthreads();
    for (int off = 1; off < SCAN_B; off <<= 1) {
        int add = (t >= off) ? sm[t - off] : 0;
        __syncthreads();
        sm[t] += add;
        __syncthreads();
    }
    if (t < nb) partials[t] = sm[t] - v;
}

__global__ void k_scan3(int* __restrict__ ex, const int* __restrict__ partials, int n) {
    int i = blockIdx.x * SCAN_B + threadIdx.x;
    if (i < n) ex[i] += partials[blockIdx.x];
}

__global__ void k_fill(const void* __restrict__ ei, const int* __restrict__ flag,
                       const int* __restrict__ rowstart, int* __restrict__ cursor,
                       int* __restrict__ colidx) {
    int i = blockIdx.x * blockDim.x + threadIdx.x;
    int is64 = (flag[0] == 0);
    if (i < N_EDGES) {
        int s = edge_at(ei, is64, 0, i);
        int d = edge_at(ei, is64, 1, i);
        int pos = rowstart[d] + atomicAdd(&cursor[d], 1);
        colidx[pos] = s;
    }
}

// ---- GEMM: Cp[r, :] = pack_bf16( (A[r,:] @ W) * dinv[r] ), f32 math ----
// 8x8 microtile (1.0 FMA per LDS byte), MT=64, KT=16.
// __launch_bounds__(.,3): ~168 VGPR cap, prevents the acc[64] scratch spill
// that round 4 measured (VGPR_Count=64, WRITE_SIZE ~1 GB of spill traffic).

template <int K, int NF>
__global__ void __launch_bounds__((64 * NF) / 64, 3)
k_gemm_s(const float* __restrict__ A, const float* __restrict__ W,
         const float* __restrict__ dinv, u32* __restrict__ Cp, int M) {
    constexpr int MT = 64;
    constexpr int KT = 16;
    constexpr int NTHREADS = MT * NF / 64;      // 128 (NF=128) or 64 (NF=64)
    constexpr int CGRPS = NF / 8;               // col groups of 4
    __shared__ float wl[KT][NF];
    __shared__ float xl[KT][MT];

    const int t = threadIdx.x;
    const int m0 = blockIdx.x * MT;
    const int c0 = (t % CGRPS) * 4;
    const int r0 = (t / CGRPS) * 4;             // 0..28

    float acc[2][2][4][4] = {};                 // [rowblk][colblk][ri][ci]

    for (int k0 = 0; k0 < K; k0 += KT) {
        // stage W chunk: consecutive lanes -> consecutive cols (coalesced, conflict-free)
        constexpr int WLOADS = KT * NF / 4;
        #pragma unroll
        for (int idx = t; idx < WLOADS; idx += NTHREADS) {
            int kk = idx / (NF / 4);
            int ff = (idx % (NF / 4)) * 4;
            *(float4*)&wl[kk][ff] = *(const float4*)&W[(k0 + kk) * NF + ff];
        }
        // stage A chunk transposed; n fastest across lanes -> conflict-free LDS stores
        constexpr int XLOADS = MT * KT / 4;
        #pragma unroll
        for (int idx = t; idx < XLOADS; idx += NTHREADS) {
            int n  = idx % MT;
            int kc = (idx / MT) * 4;
            float4 xv = make_float4(0.f, 0.f, 0.f, 0.f);
            int row = m0 + n;
            if (row < M) xv = *(const float4*)&A[row * K + k0 + kc];
            xl[kc + 0][n] = xv.x; xl[kc + 1][n] = xv.y;
            xl[kc + 2][n] = xv.z; xl[kc + 3][n] = xv.w;
        }
        __syncthreads();
        #pragma unroll
        for (int kk = 0; kk < KT; ++kk) {
            float4 xa = *(const float4*)&xl[kk][r0];
            float4 xb = *(const float4*)&xl[kk][r0 + 32];
            float4 wa = *(const float4*)&wl[kk][c0];
            float4 wb = *(const float4*)&wl[kk][c0 + NF / 2];
            const float xr[2][4] = {{xa.x, xa.y, xa.z, xa.w}, {xb.x, xb.y, xb.z, xb.w}};
            const float wc[2][4] = {{wa.x, wa.y, wa.z, wa.w}, {wb.x, wb.y, wb.z, wb.w}};
            #pragma unroll
            for (int rb = 0; rb < 2; ++rb)
                #pragma unroll
                for (int cb = 0; cb < 2; ++cb)
                    #pragma unroll
                    for (int ri = 0; ri < 4; ++ri)
                        #pragma unroll
                        for (int ci = 0; ci < 4; ++ci)
                            acc[rb][cb][ri][ci] += xr[rb][ri] * wc[cb][ci];
        }
        __syncthreads();
    }

    #pragma unroll
    for (int rb = 0; rb < 2; ++rb) {
        #pragma unroll
        for (int ri = 0; ri < 4; ++ri) {
            int row = m0 + rb * 32 + r0 + ri;
            if (row < M) {
                float s = dinv[row];
                #pragma unroll
                for (int cb = 0; cb < 2; ++cb) {
                    uint2 o;
                    o.x = pack_bf2(acc[rb][cb][ri][0] * s, acc[rb][cb][ri][1] * s);
                    o.y = pack_bf2(acc[rb][cb][ri][2] * s, acc[rb][cb][ri][3] * s);
                    *(uint2*)&Cp[(size_t)row * (NF / 2) + (c0 + cb * (NF / 2)) / 2] = o;
                }
            }
        }
    }
}

// ---------------- fused aggregate + bias (+relu) + sigmoid gate ----------------
// hs rows are pre-scaled by dinv[row]; agg = dv * (hs[v] + sum hs[neighbor]).

// layer 1: 128 feats = 64 u32/row. One wave per node; lane l = feats (2l, 2l+1).
__global__ void k_agg1(const u32* __restrict__ hs, const int* __restrict__ rowstart,
                       const int* __restrict__ cnt, const int* __restrict__ colidx,
                       const float* __restrict__ dinv,
                       const float* __restrict__ b, const float* __restrict__ aw,
                       const float* __restrict__ ab, float* __restrict__ out) {
    int v = blockIdx.x;
    int l = threadIdx.x;
    float dv = dinv[v];
    u32 su = hs[(size_t)v * 64 + l];
    float ax = bflo(su), ay = bfhi(su);
    int start = rowstart[v], len = cnt[v];
    const int* cx = colidx + start;
    int j = 0;
    for (; j + 4 <= len; j += 4) {
        int s0 = cx[j], s1 = cx[j + 1], s2 = cx[j + 2], s3 = cx[j + 3];
        u32 u0 = hs[(size_t)s0 * 64 + l];
        u32 u1 = hs[(size_t)s1 * 64 + l];
        u32 u2 = hs[(size_t)s2 * 64 + l];
        u32 u3 = hs[(size_t)s3 * 64 + l];
        ax += bflo(u0) + bflo(u1) + bflo(u2) + bflo(u3);
        ay += bfhi(u0) + bfhi(u1) + bfhi(u2) + bfhi(u3);
    }
    for (; j < len; ++j) {
        u32 u = hs[(size_t)cx[j] * 64 + l];
        ax += bflo(u); ay += bfhi(u);
    }
    float2 bp = ((const float2*)b)[l];
    ax = fmaxf(ax * dv + bp.x, 0.0f);
    ay = fmaxf(ay * dv + bp.y, 0.0f);
    float2 ap = ((const float2*)aw)[l];
    float p = ax * ap.x + ay * ap.y;
    for (int off = 32; off; off >>= 1) p += __shfl_xor(p, off);
    float g = 1.0f / (1.0f + expf(-(p + ab[0])));
    ((float2*)out)[(size_t)v * 64 + l] = make_float2(ax * g, ay * g);
}

// layer 2: 64 feats = 32 u32/row. One wave per node, 2 half-waves on
// alternating neighbors (2 rows in flight, x2 unroll = 4).
__global__ void k_agg2(const u32* __restrict__ hs, const int* __restrict__ rowstart,
                       const int* __restrict__ cnt, const int* __restrict__ colidx,
                       const float* __restrict__ dinv,
                       const float* __restrict__ b, const float* __restrict__ aw,
                       const float* __restrict__ ab, float* __restrict__ out) {
    int v = blockIdx.x;
    int l = threadIdx.x;
    int c = l & 31, half = l >> 5;
    float dv = dinv[v];
    float ax = 0.0f, ay = 0.0f;
    if (half == 0) {
        u32 su = hs[(size_t)v * 32 + c];
        ax = bflo(su); ay = bfhi(su);
    }
    int start = rowstart[v], len = cnt[v];
    const int* cx = colidx + start;
    int j = half;
    for (; j + 2 < len; j += 4) {
        int s0 = cx[j], s1 = cx[j + 2];
        u32 u0 = hs[(size_t)s0 * 32 + c];
        u32 u1 = hs[(size_t)s1 * 32 + c];
        ax += bflo(u0) + bflo(u1);
        ay += bfhi(u0) + bfhi(u1);
    }
    if (j < len) {
        u32 u = hs[(size_t)cx[j] * 32 + c];
        ax += bflo(u); ay += bfhi(u);
    }
    ax += __shfl_xor(ax, 32);
    ay += __shfl_xor(ay, 32);
    float2 bp = ((const float2*)b)[c];
    ax = ax * dv + bp.x;
    ay = ay * dv + bp.y;
    float2 ap = ((const float2*)aw)[c];
    float p = ax * ap.x + ay * ap.y;
    for (int off = 16; off; off >>= 1) p += __shfl_xor(p, off);
    float g = 1.0f / (1.0f + expf(-(p + ab[0])));
    if (half == 0) ((float2*)out)[(size_t)v * 32 + c] = make_float2(ax * g, ay * g);
}

// ---------------- launch ----------------

static inline size_t align_up(size_t x, size_t a) { return (x + a - 1) & ~(a - 1); }

extern "C" void kernel_launch(void* const* d_in, const int* in_sizes, int n_in,
                              void* d_out, int out_size, void* d_ws, size_t ws_size,
                              hipStream_t stream) {
    const float* x   = (const float*)d_in[0];
    const void*  ei  = d_in[1];
    const float* W1  = (const float*)d_in[2];
    const float* b1  = (const float*)d_in[3];
    const float* W2  = (const float*)d_in[4];
    const float* b2  = (const float*)d_in[5];
    const float* aw1 = (const float*)d_in[6];
    const float* ab1 = (const float*)d_in[7];
    const float* aw2 = (const float*)d_in[8];
    const float* ab2 = (const float*)d_in[9];
    float* out = (float*)d_out;

    char* w = (char*)d_ws;
    size_t off = 0;
    int*   flag     = (int*)(w + off); off = align_up(off + 4, 256);
    int*   cnt      = (int*)(w + off); off = align_up(off + N_NODES * 4, 256);
    int*   rowstart = (int*)(w + off); off = align_up(off + N_NODES * 4, 256);
    int*   cursor   = (int*)(w + off); off = align_up(off + N_NODES * 4, 256);
    int*   partials = (int*)(w + off); off = align_up(off + 1024 * 4, 256);
    float* dinv     = (float*)(w + off); off = align_up(off + N_NODES * 4, 256);
    int*   colidx   = (int*)(w + off); off = align_up(off + (size_t)N_EDGES * 4, 256);
    u32*   h1s      = (u32*)(w + off); off = align_up(off + (size_t)N_NODES * 64 * 4, 256);
    float* h1g      = (float*)(w + off); off = align_up(off + (size_t)N_NODES * D_HID * 4, 256);
    u32*   h2s      = (u32*)(w + off); off = align_up(off + (size_t)N_NODES * 32 * 4, 256);
    (void)ws_size; (void)out_size; (void)n_in; (void)in_sizes;

    (void)hipMemsetAsync(flag, 0, 4, stream);
    (void)hipMemsetAsync(cnt, 0, N_NODES * 4, stream);
    (void)hipMemsetAsync(cursor, 0, N_NODES * 4, stream);

    const int eb = (N_EDGES + 255) / 256;
    const int nb = (N_NODES + 255) / 256;
    const int sb = (N_NODES + SCAN_B - 1) / SCAN_B;

    k_detect<<<1, 256, 0, stream>>>(ei, flag);
    k_count<<<eb, 256, 0, stream>>>(ei, flag, cnt);
    k_dinv<<<nb, 256, 0, stream>>>(cnt, dinv);
    k_scan1<<<sb, SCAN_B, 0, stream>>>(cnt, rowstart, partials, N_NODES);
    k_scan2<<<1, SCAN_B, 0, stream>>>(partials, sb);
    k_scan3<<<sb, SCAN_B, 0, stream>>>(rowstart, partials, N_NODES);
    k_fill<<<eb, 256, 0, stream>>>(ei, flag, rowstart, cursor, colidx);

    const int gb = (N_NODES + 63) / 64;   // 782 tiles of 64 rows

    // layer 1: h1s = pack_bf16((x @ W1) * dinv)
    k_gemm_s<D_IN, D_HID><<<gb, 128, 0, stream>>>(x, W1, dinv, h1s, N_NODES);
    k_agg1<<<N_NODES, 64, 0, stream>>>(h1s, rowstart, cnt, colidx, dinv, b1, aw1, ab1, h1g);

    // layer 2: h2s = pack_bf16((h1g @ W2) * dinv)
    k_gemm_s<D_HID, D_OUT><<<gb, 64, 0, stream>>>(h1g, W2, dinv, h2s, N_NODES);
    k_agg2<<<N_NODES, 64, 0, stream>>>(h2s, rowstart, cnt, colidx, dinv, b2, aw2, ab2, out);
}

// Round 7
// 392.717 us; speedup vs baseline: 2.1503x; 1.4464x over previous
//
#include <hip/hip_runtime.h>
#include <math.h>

#define N_NODES 50000
#define N_EDGES 800000
#define D_IN    256
#define D_HID   128
#define D_OUT   64

typedef unsigned int u32;

__device__ __forceinline__ float bflo(u32 u) {
    union { u32 i; float f; } c; c.i = u << 16; return c.f;
}
__device__ __forceinline__ float bfhi(u32 u) {
    union { u32 i; float f; } c; c.i = u & 0xffff0000u; return c.f;
}
__device__ __forceinline__ u32 pack_bf2(float a, float b) {
    union { float f; u32 i; } ca, cb; ca.f = a; cb.f = b;
    u32 ra = (ca.i + 0x7fffu + ((ca.i >> 16) & 1u)) >> 16;
    u32 rb = (cb.i + 0x7fffu + ((cb.i >> 16) & 1u)) & 0xffff0000u;
    return ra | rb;
}

// ---------------- edge dtype detection ----------------
__global__ void k_detect(const void* __restrict__ ei, int* __restrict__ flag) {
    int t = threadIdx.x;
    int v = ((const int*)ei)[2 * t + 1];
    if (v != 0) atomicOr(flag, 1);
}

__device__ __forceinline__ int edge_at(const void* ei, int is64, int which, int i) {
    if (is64) return (int)((const long long*)ei)[(size_t)which * N_EDGES + i];
    return ((const int*)ei)[which * N_EDGES + i];
}

// ---------------- degree / CSR build ----------------

__global__ void k_count(const void* __restrict__ ei, const int* __restrict__ flag,
                        int* __restrict__ cnt) {
    int i = blockIdx.x * blockDim.x + threadIdx.x;
    int is64 = (flag[0] == 0);
    if (i < N_EDGES) atomicAdd(&cnt[edge_at(ei, is64, 1, i)], 1);
}

__global__ void k_dinv(const int* __restrict__ cnt, float* __restrict__ dinv) {
    int i = blockIdx.x * blockDim.x + threadIdx.x;
    if (i < N_NODES) dinv[i] = rsqrtf(1.0f + (float)cnt[i]);
}

#define SCAN_B 256
__global__ void k_scan1(const int* __restrict__ cnt, int* __restrict__ ex,
                        int* __restrict__ partials, int n) {
    __shared__ int sm[SCAN_B];
    int t = threadIdx.x;
    int i = blockIdx.x * SCAN_B + t;
    int v = (i < n) ? cnt[i] : 0;
    sm[t] = v; __syncthreads();
    for (int off = 1; off < SCAN_B; off <<= 1) {
        int add = (t >= off) ? sm[t - off] : 0;
        __syncthreads();
        sm[t] += add;
        __syncthreads();
    }
    if (i < n) ex[i] = sm[t] - v;
    if (t == SCAN_B - 1) partials[blockIdx.x] = sm[t];
}

__global__ void k_scan2(int* __restrict__ partials, int nb) {
    __shared__ int sm[SCAN_B];
    int t = threadIdx.x;
    int v = (t < nb) ? partials[t] : 0;
    sm[t] = v; __syncthreads();
    for (int off = 1; off < SCAN_B; off <<= 1) {
        int add = (t >= off) ? sm[t - off] : 0;
        __syncthreads();
        sm[t] += add;
        __syncthreads();
    }
    if (t < nb) partials[t] = sm[t] - v;
}

__global__ void k_scan3(int* __restrict__ ex, const int* __restrict__ partials, int n) {
    int i = blockIdx.x * SCAN_B + threadIdx.x;
    if (i < n) ex[i] += partials[blockIdx.x];
}

__global__ void k_fill(const void* __restrict__ ei, const int* __restrict__ flag,
                       const int* __restrict__ rowstart, int* __restrict__ cursor,
                       int* __restrict__ colidx) {
    int i = blockIdx.x * blockDim.x + threadIdx.x;
    int is64 = (flag[0] == 0);
    if (i < N_EDGES) {
        int s = edge_at(ei, is64, 0, i);
        int d = edge_at(ei, is64, 1, i);
        int pos = rowstart[d] + atomicAdd(&cursor[d], 1);
        colidx[pos] = s;
    }
}

// ---- GEMM: Cp[r, :] = pack_bf16( (A[r,:] @ W) * dinv[r] ), f32 math ----
// 8x8 microtile (1.0 FMA per LDS byte), MT=64, KT=16.
// __launch_bounds__(., 1): HIP treats arg2 as workgroups/EU (measured: r4 none
// ->64 VGPR spill; r6 min=3 -> 84 = 512/6 spill). min=1 => cap 256, no spill.

template <int K, int NF>
__global__ void __launch_bounds__((64 * NF) / 64, 1)
k_gemm_s(const float* __restrict__ A, const float* __restrict__ W,
         const float* __restrict__ dinv, u32* __restrict__ Cp, int M) {
    constexpr int MT = 64;
    constexpr int KT = 16;
    constexpr int NTHREADS = MT * NF / 64;      // 128 (NF=128) or 64 (NF=64)
    constexpr int CGRPS = NF / 8;               // col groups of 4
    __shared__ float wl[KT][NF];
    __shared__ float xl[KT][MT];

    const int t = threadIdx.x;
    const int m0 = blockIdx.x * MT;
    const int c0 = (t % CGRPS) * 4;
    const int r0 = (t / CGRPS) * 4;             // 0..28

    float acc[2][2][4][4] = {};                 // [rowblk][colblk][ri][ci]

    for (int k0 = 0; k0 < K; k0 += KT) {
        // stage W chunk: consecutive lanes -> consecutive cols (coalesced, conflict-free)
        constexpr int WLOADS = KT * NF / 4;
        #pragma unroll
        for (int idx = t; idx < WLOADS; idx += NTHREADS) {
            int kk = idx / (NF / 4);
            int ff = (idx % (NF / 4)) * 4;
            *(float4*)&wl[kk][ff] = *(const float4*)&W[(k0 + kk) * NF + ff];
        }
        // stage A chunk transposed; n fastest across lanes -> conflict-free LDS stores
        constexpr int XLOADS = MT * KT / 4;
        #pragma unroll
        for (int idx = t; idx < XLOADS; idx += NTHREADS) {
            int n  = idx % MT;
            int kc = (idx / MT) * 4;
            float4 xv = make_float4(0.f, 0.f, 0.f, 0.f);
            int row = m0 + n;
            if (row < M) xv = *(const float4*)&A[row * K + k0 + kc];
            xl[kc + 0][n] = xv.x; xl[kc + 1][n] = xv.y;
            xl[kc + 2][n] = xv.z; xl[kc + 3][n] = xv.w;
        }
        __syncthreads();
        #pragma unroll
        for (int kk = 0; kk < KT; ++kk) {
            float4 xa = *(const float4*)&xl[kk][r0];
            float4 xb = *(const float4*)&xl[kk][r0 + 32];
            float4 wa = *(const float4*)&wl[kk][c0];
            float4 wb = *(const float4*)&wl[kk][c0 + NF / 2];
            const float xr[2][4] = {{xa.x, xa.y, xa.z, xa.w}, {xb.x, xb.y, xb.z, xb.w}};
            const float wc[2][4] = {{wa.x, wa.y, wa.z, wa.w}, {wb.x, wb.y, wb.z, wb.w}};
            #pragma unroll
            for (int rb = 0; rb < 2; ++rb)
                #pragma unroll
                for (int cb = 0; cb < 2; ++cb)
                    #pragma unroll
                    for (int ri = 0; ri < 4; ++ri)
                        #pragma unroll
                        for (int ci = 0; ci < 4; ++ci)
                            acc[rb][cb][ri][ci] += xr[rb][ri] * wc[cb][ci];
        }
        __syncthreads();
    }

    #pragma unroll
    for (int rb = 0; rb < 2; ++rb) {
        #pragma unroll
        for (int ri = 0; ri < 4; ++ri) {
            int row = m0 + rb * 32 + r0 + ri;
            if (row < M) {
                float s = dinv[row];
                #pragma unroll
                for (int cb = 0; cb < 2; ++cb) {
                    uint2 o;
                    o.x = pack_bf2(acc[rb][cb][ri][0] * s, acc[rb][cb][ri][1] * s);
                    o.y = pack_bf2(acc[rb][cb][ri][2] * s, acc[rb][cb][ri][3] * s);
                    *(uint2*)&Cp[(size_t)row * (NF / 2) + (c0 + cb * (NF / 2)) / 2] = o;
                }
            }
        }
    }
}

// ---------------- fused aggregate + bias (+relu) + sigmoid gate ----------------
// hs rows are pre-scaled by dinv[row]; agg = dv * (hs[v] + sum hs[neighbor]).

// layer 1: 128 feats = 64 u32/row. One wave per node; lane l = feats (2l, 2l+1).
__global__ void k_agg1(const u32* __restrict__ hs, const int* __restrict__ rowstart,
                       const int* __restrict__ cnt, const int* __restrict__ colidx,
                       const float* __restrict__ dinv,
                       const float* __restrict__ b, const float* __restrict__ aw,
                       const float* __restrict__ ab, float* __restrict__ out) {
    int v = blockIdx.x;
    int l = threadIdx.x;
    float dv = dinv[v];
    u32 su = hs[(size_t)v * 64 + l];
    float ax = bflo(su), ay = bfhi(su);
    int start = rowstart[v], len = cnt[v];
    const int* cx = colidx + start;
    int j = 0;
    for (; j + 4 <= len; j += 4) {
        int s0 = cx[j], s1 = cx[j + 1], s2 = cx[j + 2], s3 = cx[j + 3];
        u32 u0 = hs[(size_t)s0 * 64 + l];
        u32 u1 = hs[(size_t)s1 * 64 + l];
        u32 u2 = hs[(size_t)s2 * 64 + l];
        u32 u3 = hs[(size_t)s3 * 64 + l];
        ax += bflo(u0) + bflo(u1) + bflo(u2) + bflo(u3);
        ay += bfhi(u0) + bfhi(u1) + bfhi(u2) + bfhi(u3);
    }
    for (; j < len; ++j) {
        u32 u = hs[(size_t)cx[j] * 64 + l];
        ax += bflo(u); ay += bfhi(u);
    }
    float2 bp = ((const float2*)b)[l];
    ax = fmaxf(ax * dv + bp.x, 0.0f);
    ay = fmaxf(ay * dv + bp.y, 0.0f);
    float2 ap = ((const float2*)aw)[l];
    float p = ax * ap.x + ay * ap.y;
    for (int off = 32; off; off >>= 1) p += __shfl_xor(p, off);
    float g = 1.0f / (1.0f + expf(-(p + ab[0])));
    ((float2*)out)[(size_t)v * 64 + l] = make_float2(ax * g, ay * g);
}

// layer 2: 64 feats = 32 u32/row. One wave per node, 2 half-waves on
// alternating neighbors (2 rows in flight, x2 unroll = 4).
__global__ void k_agg2(const u32* __restrict__ hs, const int* __restrict__ rowstart,
                       const int* __restrict__ cnt, const int* __restrict__ colidx,
                       const float* __restrict__ dinv,
                       const float* __restrict__ b, const float* __restrict__ aw,
                       const float* __restrict__ ab, float* __restrict__ out) {
    int v = blockIdx.x;
    int l = threadIdx.x;
    int c = l & 31, half = l >> 5;
    float dv = dinv[v];
    float ax = 0.0f, ay = 0.0f;
    if (half == 0) {
        u32 su = hs[(size_t)v * 32 + c];
        ax = bflo(su); ay = bfhi(su);
    }
    int start = rowstart[v], len = cnt[v];
    const int* cx = colidx + start;
    int j = half;
    for (; j + 2 < len; j += 4) {
        int s0 = cx[j], s1 = cx[j + 2];
        u32 u0 = hs[(size_t)s0 * 32 + c];
        u32 u1 = hs[(size_t)s1 * 32 + c];
        ax += bflo(u0) + bflo(u1);
        ay += bfhi(u0) + bfhi(u1);
    }
    if (j < len) {
        u32 u = hs[(size_t)cx[j] * 32 + c];
        ax += bflo(u); ay += bfhi(u);
    }
    ax += __shfl_xor(ax, 32);
    ay += __shfl_xor(ay, 32);
    float2 bp = ((const float2*)b)[c];
    ax = ax * dv + bp.x;
    ay = ay * dv + bp.y;
    float2 ap = ((const float2*)aw)[c];
    float p = ax * ap.x + ay * ap.y;
    for (int off = 16; off; off >>= 1) p += __shfl_xor(p, off);
    float g = 1.0f / (1.0f + expf(-(p + ab[0])));
    if (half == 0) ((float2*)out)[(size_t)v * 32 + c] = make_float2(ax * g, ay * g);
}

// ---------------- launch ----------------

static inline size_t align_up(size_t x, size_t a) { return (x + a - 1) & ~(a - 1); }

extern "C" void kernel_launch(void* const* d_in, const int* in_sizes, int n_in,
                              void* d_out, int out_size, void* d_ws, size_t ws_size,
                              hipStream_t stream) {
    const float* x   = (const float*)d_in[0];
    const void*  ei  = d_in[1];
    const float* W1  = (const float*)d_in[2];
    const float* b1  = (const float*)d_in[3];
    const float* W2  = (const float*)d_in[4];
    const float* b2  = (const float*)d_in[5];
    const float* aw1 = (const float*)d_in[6];
    const float* ab1 = (const float*)d_in[7];
    const float* aw2 = (const float*)d_in[8];
    const float* ab2 = (const float*)d_in[9];
    float* out = (float*)d_out;

    char* w = (char*)d_ws;
    size_t off = 0;
    int*   flag     = (int*)(w + off); off = align_up(off + 4, 256);
    int*   cnt      = (int*)(w + off); off = align_up(off + N_NODES * 4, 256);
    int*   rowstart = (int*)(w + off); off = align_up(off + N_NODES * 4, 256);
    int*   cursor   = (int*)(w + off); off = align_up(off + N_NODES * 4, 256);
    int*   partials = (int*)(w + off); off = align_up(off + 1024 * 4, 256);
    float* dinv     = (float*)(w + off); off = align_up(off + N_NODES * 4, 256);
    int*   colidx   = (int*)(w + off); off = align_up(off + (size_t)N_EDGES * 4, 256);
    u32*   h1s      = (u32*)(w + off); off = align_up(off + (size_t)N_NODES * 64 * 4, 256);
    float* h1g      = (float*)(w + off); off = align_up(off + (size_t)N_NODES * D_HID * 4, 256);
    u32*   h2s      = (u32*)(w + off); off = align_up(off + (size_t)N_NODES * 32 * 4, 256);
    (void)ws_size; (void)out_size; (void)n_in; (void)in_sizes;

    (void)hipMemsetAsync(flag, 0, 4, stream);
    (void)hipMemsetAsync(cnt, 0, N_NODES * 4, stream);
    (void)hipMemsetAsync(cursor, 0, N_NODES * 4, stream);

    const int eb = (N_EDGES + 255) / 256;
    const int nb = (N_NODES + 255) / 256;
    const int sb = (N_NODES + SCAN_B - 1) / SCAN_B;

    k_detect<<<1, 256, 0, stream>>>(ei, flag);
    k_count<<<eb, 256, 0, stream>>>(ei, flag, cnt);
    k_dinv<<<nb, 256, 0, stream>>>(cnt, dinv);
    k_scan1<<<sb, SCAN_B, 0, stream>>>(cnt, rowstart, partials, N_NODES);
    k_scan2<<<1, SCAN_B, 0, stream>>>(partials, sb);
    k_scan3<<<sb, SCAN_B, 0, stream>>>(rowstart, partials, N_NODES);
    k_fill<<<eb, 256, 0, stream>>>(ei, flag, rowstart, cursor, colidx);

    const int gb = (N_NODES + 63) / 64;   // 782 tiles of 64 rows

    // layer 1: h1s = pack_bf16((x @ W1) * dinv)
    k_gemm_s<D_IN, D_HID><<<gb, 128, 0, stream>>>(x, W1, dinv, h1s, N_NODES);
    k_agg1<<<N_NODES, 64, 0, stream>>>(h1s, rowstart, cnt, colidx, dinv, b1, aw1, ab1, h1g);

    // layer 2: h2s = pack_bf16((h1g @ W2) * dinv)
    k_gemm_s<D_HID, D_OUT><<<gb, 64, 0, stream>>>(h1g, W2, dinv, h2s, N_NODES);
    k_agg2<<<N_NODES, 64, 0, stream>>>(h2s, rowstart, cnt, colidx, dinv, b2, aw2, ab2, out);
}

// Round 8
// 348.311 us; speedup vs baseline: 2.4244x; 1.1275x over previous
//
#include <hip/hip_runtime.h>
#include <math.h>

#define N_NODES 50000
#define N_EDGES 800000
#define D_IN    256
#define D_HID   128
#define D_OUT   64

typedef unsigned int u32;

__device__ __forceinline__ float bflo(u32 u) {
    union { u32 i; float f; } c; c.i = u << 16; return c.f;
}
__device__ __forceinline__ float bfhi(u32 u) {
    union { u32 i; float f; } c; c.i = u & 0xffff0000u; return c.f;
}
__device__ __forceinline__ u32 pack_bf2(float a, float b) {
    union { float f; u32 i; } ca, cb; ca.f = a; cb.f = b;
    u32 ra = (ca.i + 0x7fffu + ((ca.i >> 16) & 1u)) >> 16;
    u32 rb = (cb.i + 0x7fffu + ((cb.i >> 16) & 1u)) & 0xffff0000u;
    return ra | rb;
}

// ---------------- edge dtype detection ----------------
__global__ void k_detect(const void* __restrict__ ei, int* __restrict__ flag) {
    int t = threadIdx.x;
    int v = ((const int*)ei)[2 * t + 1];
    if (v != 0) atomicOr(flag, 1);
}

__device__ __forceinline__ int edge_at(const void* ei, int is64, int which, int i) {
    if (is64) return (int)((const long long*)ei)[(size_t)which * N_EDGES + i];
    return ((const int*)ei)[which * N_EDGES + i];
}

// ---------------- degree / CSR build ----------------

__global__ void k_count(const void* __restrict__ ei, const int* __restrict__ flag,
                        int* __restrict__ cnt) {
    int i = blockIdx.x * blockDim.x + threadIdx.x;
    int is64 = (flag[0] == 0);
    if (i < N_EDGES) atomicAdd(&cnt[edge_at(ei, is64, 1, i)], 1);
}

__global__ void k_dinv(const int* __restrict__ cnt, float* __restrict__ dinv) {
    int i = blockIdx.x * blockDim.x + threadIdx.x;
    if (i < N_NODES) dinv[i] = rsqrtf(1.0f + (float)cnt[i]);
}

#define SCAN_B 256
__global__ void k_scan1(const int* __restrict__ cnt, int* __restrict__ ex,
                        int* __restrict__ partials, int n) {
    __shared__ int sm[SCAN_B];
    int t = threadIdx.x;
    int i = blockIdx.x * SCAN_B + t;
    int v = (i < n) ? cnt[i] : 0;
    sm[t] = v; __syncthreads();
    for (int off = 1; off < SCAN_B; off <<= 1) {
        int add = (t >= off) ? sm[t - off] : 0;
        __syncthreads();
        sm[t] += add;
        __syncthreads();
    }
    if (i < n) ex[i] = sm[t] - v;
    if (t == SCAN_B - 1) partials[blockIdx.x] = sm[t];
}

__global__ void k_scan2(int* __restrict__ partials, int nb) {
    __shared__ int sm[SCAN_B];
    int t = threadIdx.x;
    int v = (t < nb) ? partials[t] : 0;
    sm[t] = v; __syncthreads();
    for (int off = 1; off < SCAN_B; off <<= 1) {
        int add = (t >= off) ? sm[t - off] : 0;
        __syncthreads();
        sm[t] += add;
        __syncthreads();
    }
    if (t < nb) partials[t] = sm[t] - v;
}

__global__ void k_scan3(int* __restrict__ ex, const int* __restrict__ partials, int n) {
    int i = blockIdx.x * SCAN_B + threadIdx.x;
    if (i < n) ex[i] += partials[blockIdx.x];
}

__global__ void k_fill(const void* __restrict__ ei, const int* __restrict__ flag,
                       const int* __restrict__ rowstart, int* __restrict__ cursor,
                       int* __restrict__ colidx) {
    int i = blockIdx.x * blockDim.x + threadIdx.x;
    int is64 = (flag[0] == 0);
    if (i < N_EDGES) {
        int s = edge_at(ei, is64, 0, i);
        int d = edge_at(ei, is64, 1, i);
        int pos = rowstart[d] + atomicAdd(&cursor[d], 1);
        colidx[pos] = s;
    }
}

// ---- GEMM: Cp[r, :] = pack_bf16( (A[r,:] @ W) * dinv[r] ), f32 math ----
// Round-8 structure: 256 threads (4 waves) per 64-row tile, 4x(NF/16) microtile,
// register-staged DOUBLE-BUFFERED LDS pipeline (1 barrier/tile, next tile's
// global loads issued before compute -> latency hidden). r7 measured the
// single-buffered 2-wave version latency-starved: VALUBusy 22%, occ 8.3%.
// LDS reads: xl broadcast across 16 lanes, wl <=2-way aliasing (free, m136).

template <int K, int NF>
__global__ void __launch_bounds__(256, 1)
k_gemm_s(const float* __restrict__ A, const float* __restrict__ W,
         const float* __restrict__ dinv, u32* __restrict__ Cp, int M) {
    constexpr int MT = 64;
    constexpr int KT = 16;
    constexpr int CB = NF / 64;                  // col blocks per thread (2 or 1)
    constexpr int WIT = (KT * NF / 4) / 256;     // W float4 loads per thread (2 or 1)
    constexpr int NT = K / KT;                   // K tiles
    __shared__ float wl[2][KT][NF];
    __shared__ float xl[2][KT][MT];

    const int t  = threadIdx.x;
    const int m0 = blockIdx.x * MT;
    const int c0 = (t % 16) * 4;                 // cols c0..c0+3 (+64 for CB=2)
    const int r0 = (t / 16) * 4;                 // rows r0..r0+3 (0..60)

    float4 wreg[WIT];
    float4 areg;

    const int an = t % MT;                       // A row within tile
    const int akc = (t / MT) * 4;                // A k-offset within tile

    // prologue: stage tile 0 into registers
    {
        #pragma unroll
        for (int i = 0; i < WIT; ++i) {
            int idx = t + 256 * i;
            int kk = idx / (NF / 4);
            int ff = (idx % (NF / 4)) * 4;
            wreg[i] = *(const float4*)&W[kk * NF + ff];
        }
        int row = m0 + an;
        areg = (row < M) ? *(const float4*)&A[(size_t)row * K + akc]
                         : make_float4(0.f, 0.f, 0.f, 0.f);
    }

    float acc[CB][4][4] = {};
    int cur = 0;

    for (int tile = 0; tile < NT; ++tile) {
        // commit staged registers to LDS (compiler inserts vmcnt wait)
        #pragma unroll
        for (int i = 0; i < WIT; ++i) {
            int idx = t + 256 * i;
            int kk = idx / (NF / 4);
            int ff = (idx % (NF / 4)) * 4;
            *(float4*)&wl[cur][kk][ff] = wreg[i];
        }
        xl[cur][akc + 0][an] = areg.x;
        xl[cur][akc + 1][an] = areg.y;
        xl[cur][akc + 2][an] = areg.z;
        xl[cur][akc + 3][an] = areg.w;
        __syncthreads();

        // issue next tile's global loads (no wait -> overlap with compute)
        if (tile + 1 < NT) {
            int k0 = (tile + 1) * KT;
            #pragma unroll
            for (int i = 0; i < WIT; ++i) {
                int idx = t + 256 * i;
                int kk = idx / (NF / 4);
                int ff = (idx % (NF / 4)) * 4;
                wreg[i] = *(const float4*)&W[(size_t)(k0 + kk) * NF + ff];
            }
            int row = m0 + an;
            areg = (row < M) ? *(const float4*)&A[(size_t)row * K + k0 + akc]
                             : make_float4(0.f, 0.f, 0.f, 0.f);
        }

        // compute current tile
        #pragma unroll
        for (int kk = 0; kk < KT; ++kk) {
            float4 xa = *(const float4*)&xl[cur][kk][r0];
            const float xr[4] = {xa.x, xa.y, xa.z, xa.w};
            #pragma unroll
            for (int cb = 0; cb < CB; ++cb) {
                float4 wv = *(const float4*)&wl[cur][kk][c0 + cb * 64];
                const float wc[4] = {wv.x, wv.y, wv.z, wv.w};
                #pragma unroll
                for (int ri = 0; ri < 4; ++ri)
                    #pragma unroll
                    for (int ci = 0; ci < 4; ++ci)
                        acc[cb][ri][ci] += xr[ri] * wc[ci];
            }
        }
        cur ^= 1;
    }

    #pragma unroll
    for (int ri = 0; ri < 4; ++ri) {
        int row = m0 + r0 + ri;
        if (row < M) {
            float s = dinv[row];
            #pragma unroll
            for (int cb = 0; cb < CB; ++cb) {
                uint2 o;
                o.x = pack_bf2(acc[cb][ri][0] * s, acc[cb][ri][1] * s);
                o.y = pack_bf2(acc[cb][ri][2] * s, acc[cb][ri][3] * s);
                *(uint2*)&Cp[(size_t)row * (NF / 2) + (c0 + cb * 64) / 2] = o;
            }
        }
    }
}

// ---------------- fused aggregate + bias (+relu) + sigmoid gate ----------------
// hs rows are pre-scaled by dinv[row]; agg = dv * (hs[v] + sum hs[neighbor]).

// layer 1: 128 feats = 64 u32/row. One wave per node; lane l = feats (2l, 2l+1).
__global__ void k_agg1(const u32* __restrict__ hs, const int* __restrict__ rowstart,
                       const int* __restrict__ cnt, const int* __restrict__ colidx,
                       const float* __restrict__ dinv,
                       const float* __restrict__ b, const float* __restrict__ aw,
                       const float* __restrict__ ab, float* __restrict__ out) {
    int v = blockIdx.x;
    int l = threadIdx.x;
    float dv = dinv[v];
    u32 su = hs[(size_t)v * 64 + l];
    float ax = bflo(su), ay = bfhi(su);
    int start = rowstart[v], len = cnt[v];
    const int* cx = colidx + start;
    int j = 0;
    for (; j + 4 <= len; j += 4) {
        int s0 = cx[j], s1 = cx[j + 1], s2 = cx[j + 2], s3 = cx[j + 3];
        u32 u0 = hs[(size_t)s0 * 64 + l];
        u32 u1 = hs[(size_t)s1 * 64 + l];
        u32 u2 = hs[(size_t)s2 * 64 + l];
        u32 u3 = hs[(size_t)s3 * 64 + l];
        ax += bflo(u0) + bflo(u1) + bflo(u2) + bflo(u3);
        ay += bfhi(u0) + bfhi(u1) + bfhi(u2) + bfhi(u3);
    }
    for (; j < len; ++j) {
        u32 u = hs[(size_t)cx[j] * 64 + l];
        ax += bflo(u); ay += bfhi(u);
    }
    float2 bp = ((const float2*)b)[l];
    ax = fmaxf(ax * dv + bp.x, 0.0f);
    ay = fmaxf(ay * dv + bp.y, 0.0f);
    float2 ap = ((const float2*)aw)[l];
    float p = ax * ap.x + ay * ap.y;
    for (int off = 32; off; off >>= 1) p += __shfl_xor(p, off);
    float g = 1.0f / (1.0f + expf(-(p + ab[0])));
    ((float2*)out)[(size_t)v * 64 + l] = make_float2(ax * g, ay * g);
}

// layer 2: 64 feats = 32 u32/row. One wave per node, 2 half-waves on
// alternating neighbors (2 rows in flight, x2 unroll = 4).
__global__ void k_agg2(const u32* __restrict__ hs, const int* __restrict__ rowstart,
                       const int* __restrict__ cnt, const int* __restrict__ colidx,
                       const float* __restrict__ dinv,
                       const float* __restrict__ b, const float* __restrict__ aw,
                       const float* __restrict__ ab, float* __restrict__ out) {
    int v = blockIdx.x;
    int l = threadIdx.x;
    int c = l & 31, half = l >> 5;
    float dv = dinv[v];
    float ax = 0.0f, ay = 0.0f;
    if (half == 0) {
        u32 su = hs[(size_t)v * 32 + c];
        ax = bflo(su); ay = bfhi(su);
    }
    int start = rowstart[v], len = cnt[v];
    const int* cx = colidx + start;
    int j = half;
    for (; j + 2 < len; j += 4) {
        int s0 = cx[j], s1 = cx[j + 2];
        u32 u0 = hs[(size_t)s0 * 32 + c];
        u32 u1 = hs[(size_t)s1 * 32 + c];
        ax += bflo(u0) + bflo(u1);
        ay += bfhi(u0) + bfhi(u1);
    }
    if (j < len) {
        u32 u = hs[(size_t)cx[j] * 32 + c];
        ax += bflo(u); ay += bfhi(u);
    }
    ax += __shfl_xor(ax, 32);
    ay += __shfl_xor(ay, 32);
    float2 bp = ((const float2*)b)[c];
    ax = ax * dv + bp.x;
    ay = ay * dv + bp.y;
    float2 ap = ((const float2*)aw)[c];
    float p = ax * ap.x + ay * ap.y;
    for (int off = 16; off; off >>= 1) p += __shfl_xor(p, off);
    float g = 1.0f / (1.0f + expf(-(p + ab[0])));
    if (half == 0) ((float2*)out)[(size_t)v * 32 + c] = make_float2(ax * g, ay * g);
}

// ---------------- launch ----------------

static inline size_t align_up(size_t x, size_t a) { return (x + a - 1) & ~(a - 1); }

extern "C" void kernel_launch(void* const* d_in, const int* in_sizes, int n_in,
                              void* d_out, int out_size, void* d_ws, size_t ws_size,
                              hipStream_t stream) {
    const float* x   = (const float*)d_in[0];
    const void*  ei  = d_in[1];
    const float* W1  = (const float*)d_in[2];
    const float* b1  = (const float*)d_in[3];
    const float* W2  = (const float*)d_in[4];
    const float* b2  = (const float*)d_in[5];
    const float* aw1 = (const float*)d_in[6];
    const float* ab1 = (const float*)d_in[7];
    const float* aw2 = (const float*)d_in[8];
    const float* ab2 = (const float*)d_in[9];
    float* out = (float*)d_out;

    char* w = (char*)d_ws;
    size_t off = 0;
    int*   flag     = (int*)(w + off); off = align_up(off + 4, 256);
    int*   cnt      = (int*)(w + off); off = align_up(off + N_NODES * 4, 256);
    int*   rowstart = (int*)(w + off); off = align_up(off + N_NODES * 4, 256);
    int*   cursor   = (int*)(w + off); off = align_up(off + N_NODES * 4, 256);
    int*   partials = (int*)(w + off); off = align_up(off + 1024 * 4, 256);
    float* dinv     = (float*)(w + off); off = align_up(off + N_NODES * 4, 256);
    int*   colidx   = (int*)(w + off); off = align_up(off + (size_t)N_EDGES * 4, 256);
    u32*   h1s      = (u32*)(w + off); off = align_up(off + (size_t)N_NODES * 64 * 4, 256);
    float* h1g      = (float*)(w + off); off = align_up(off + (size_t)N_NODES * D_HID * 4, 256);
    u32*   h2s      = (u32*)(w + off); off = align_up(off + (size_t)N_NODES * 32 * 4, 256);
    (void)ws_size; (void)out_size; (void)n_in; (void)in_sizes;

    (void)hipMemsetAsync(flag, 0, 4, stream);
    (void)hipMemsetAsync(cnt, 0, N_NODES * 4, stream);
    (void)hipMemsetAsync(cursor, 0, N_NODES * 4, stream);

    const int eb = (N_EDGES + 255) / 256;
    const int nb = (N_NODES + 255) / 256;
    const int sb = (N_NODES + SCAN_B - 1) / SCAN_B;

    k_detect<<<1, 256, 0, stream>>>(ei, flag);
    k_count<<<eb, 256, 0, stream>>>(ei, flag, cnt);
    k_dinv<<<nb, 256, 0, stream>>>(cnt, dinv);
    k_scan1<<<sb, SCAN_B, 0, stream>>>(cnt, rowstart, partials, N_NODES);
    k_scan2<<<1, SCAN_B, 0, stream>>>(partials, sb);
    k_scan3<<<sb, SCAN_B, 0, stream>>>(rowstart, partials, N_NODES);
    k_fill<<<eb, 256, 0, stream>>>(ei, flag, rowstart, cursor, colidx);

    const int gb = (N_NODES + 63) / 64;   // 782 tiles of 64 rows

    // layer 1: h1s = pack_bf16((x @ W1) * dinv)
    k_gemm_s<D_IN, D_HID><<<gb, 256, 0, stream>>>(x, W1, dinv, h1s, N_NODES);
    k_agg1<<<N_NODES, 64, 0, stream>>>(h1s, rowstart, cnt, colidx, dinv, b1, aw1, ab1, h1g);

    // layer 2: h2s = pack_bf16((h1g @ W2) * dinv)
    k_gemm_s<D_HID, D_OUT><<<gb, 256, 0, stream>>>(h1g, W2, dinv, h2s, N_NODES);
    k_agg2<<<N_NODES, 64, 0, stream>>>(h2s, rowstart, cnt, colidx, dinv, b2, aw2, ab2, out);
}